// Round 13
// baseline (163.725 us; speedup 1.0000x reference)
//
#include <hip/hip_runtime.h>
#include <hip/hip_bf16.h>
#include <stdint.h>

#define M_TOT 16384
#define N_TOT 2048
#define K_TOT 2048
#define NT 32            // K-tiles of BK=64
#define QW_BLOCKS 1024   // quant_w blocks (4096 tiles / 4 waves per block)

typedef __attribute__((ext_vector_type(8))) short bf16x8;
typedef __attribute__((ext_vector_type(4))) float f32x4;

__device__ __forceinline__ ushort f32_to_bf16_rne(float f) {
    uint32_t u = __float_as_uint(f);
    uint32_t r = (u + 0x7fffu + ((u >> 16) & 1u)) >> 16;
    return (ushort)r;
}

__device__ __forceinline__ void async_copy16(const void* gptr, void* lptr) {
    __builtin_amdgcn_global_load_lds(
        (const __attribute__((address_space(1))) uint32_t*)gptr,
        (__attribute__((address_space(3))) uint32_t*)lptr,
        16, 0, 0);
}

// ---------------------------------------------------------------------------
// Merged fake-quant kernel (R12, unchanged).
// ---------------------------------------------------------------------------
__global__ void quant_fused_kernel(const float* __restrict__ x,
                                   const float* __restrict__ w,
                                   ushort* __restrict__ qx,
                                   ushort* __restrict__ qw) {
    if (blockIdx.x < QW_BLOCKS) {
        const int gtid = blockIdx.x * 256 + threadIdx.x;
        const int wid  = gtid >> 6;
        const int lane = gtid & 63;
        const int tn = wid >> 6;
        const int tk = wid & 63;
        const int row = tn * 32 + (lane >> 1);
        const int col = tk * 32 + ((lane & 1) << 4);
        const float* p = w + (size_t)row * K_TOT + col;
        const float4 v0 = ((const float4*)p)[0];
        const float4 v1 = ((const float4*)p)[1];
        const float4 v2 = ((const float4*)p)[2];
        const float4 v3 = ((const float4*)p)[3];
        float m = 0.f;
#define MAX4(V) m = fmaxf(m, fmaxf(fmaxf(fabsf(V.x), fabsf(V.y)), fmaxf(fabsf(V.z), fabsf(V.w))));
        MAX4(v0) MAX4(v1) MAX4(v2) MAX4(v3)
#undef MAX4
        #pragma unroll
        for (int off = 1; off < 64; off <<= 1) m = fmaxf(m, __shfl_xor(m, off));
        const float s = (m > 0.f) ? (m / 127.f) : 1.f;
        float vv[16] = {v0.x, v0.y, v0.z, v0.w, v1.x, v1.y, v1.z, v1.w,
                        v2.x, v2.y, v2.z, v2.w, v3.x, v3.y, v3.z, v3.w};
        union { ushort us[16]; uint4 q[2]; } o;
        #pragma unroll
        for (int i = 0; i < 16; ++i) {
            const float q = fminf(fmaxf(rintf(vv[i] / s), -127.f), 127.f) * s;
            o.us[i] = f32_to_bf16_rne(q);
        }
        uint4* dst = (uint4*)(qw + (size_t)row * K_TOT + col);
        dst[0] = o.q[0];
        dst[1] = o.q[1];
    } else {
        const int tid = (blockIdx.x - QW_BLOCKS) * 256 + threadIdx.x;
        const float4 v = ((const float4*)x)[tid];
        float m = fmaxf(fmaxf(fabsf(v.x), fabsf(v.y)), fmaxf(fabsf(v.z), fabsf(v.w)));
        m = fmaxf(m, __shfl_xor(m, 1));
        m = fmaxf(m, __shfl_xor(m, 2));
        m = fmaxf(m, __shfl_xor(m, 4));
        const float s = (m > 0.f) ? (m / 127.f) : 1.f;
        const float q0 = fminf(fmaxf(rintf(v.x / s), -127.f), 127.f) * s;
        const float q1 = fminf(fmaxf(rintf(v.y / s), -127.f), 127.f) * s;
        const float q2 = fminf(fmaxf(rintf(v.z / s), -127.f), 127.f) * s;
        const float q3 = fminf(fmaxf(rintf(v.w / s), -127.f), 127.f) * s;
        ushort4 r;
        r.x = f32_to_bf16_rne(q0);
        r.y = f32_to_bf16_rne(q1);
        r.z = f32_to_bf16_rne(q2);
        r.w = f32_to_bf16_rne(q3);
        ((ushort4*)qx)[tid] = r;
    }
}

// ---------------------------------------------------------------------------
// 256x256 bf16 GEMM — R9 hazard structure (B 3-slot, 1 barrier/tile,
// vmcnt(4) keeps B(t+2)) with the 4 phases split into 8 sub-phases of
// 8 MFMA so every lgkm drain except s00's covers >=1-subphase-old reads.
// Issue/drain trace (per wave): s00 issues af0,bg01 | bg23,af1 (pinned) ->
// lgkm(8) drains af0+bg01; s01 issues af2 -> lgkm(8) drains bg23; s10 issues
// af3 -> lgkm(8) drains af1; s11 none; s20 lgkm(4) drains af2; s21 none;
// s30 lgkm(0) drains af3 (2 subphases old); s31 none.  3 af register sets
// (af3 reuses set P after af0's last use at s01 -- safe by program order).
// Staging: A(t+1) 1 call per s0x/s1x, B(t+2) 1 call per s2x/s3x.
// ---------------------------------------------------------------------------
#define LDSA(tb, row, colus) \
    (*(const bf16x8*)&As[tb][row][(colus) ^ (((row) & 7) << 3)])
#define LDSB(slot, row, colus) \
    (*(const bf16x8*)&Bs[slot][row][(colus) ^ (((row) & 7) << 3)])

#define STAGE_A(tb, hh, li, tt)                                                          \
    async_copy16(Agbase + (size_t)((hh) * 128 + (li) * 64) * K_TOT + (size_t)(tt) * 64,  \
                 (char*)&As[0][0][0] + (tb) * 32768 + (hh) * 16384 + (li) * 8192 + (wv << 10));
#define STAGE_B(slot, hh, li, tt)                                                        \
    async_copy16(Bgbase + (size_t)((hh) * 128 + (li) * 64) * K_TOT + (size_t)(tt) * 64,  \
                 (char*)&Bs[0][0][0] + (size_t)(slot) * 32768 + (hh) * 16384 + (li) * 8192 + (wv << 10));

#define WAITLG(N) { asm volatile("s_waitcnt lgkmcnt(" #N ")" ::: "memory"); __builtin_amdgcn_sched_barrier(0); }

// 4 A-fragments of row-pair q (rows q*32, q*32+16; k lo/hi halves)
#define RD_AF(DST, tb, q) {                                   \
    DST[0] = LDSA(tb, ab + (q) * 32,      h8);                \
    DST[1] = LDSA(tb, ab + (q) * 32,      32 + h8);           \
    DST[2] = LDSA(tb, ab + (q) * 32 + 16, h8);                \
    DST[3] = LDSA(tb, ab + (q) * 32 + 16, 32 + h8); }

// 2 n-groups (j0, j0+1) of B fragments from slot
#define RD_BGH(slot, j0) {                                                    \
    const int bbA = wcn * 64 + (j0) * 16 + r;                                 \
    bg[j0][0] = LDSB(slot, bbA, h8);  bg[j0][1] = LDSB(slot, bbA, 32 + h8);   \
    const int bbB = wcn * 64 + ((j0) + 1) * 16 + r;                           \
    bg[(j0)+1][0] = LDSB(slot, bbB, h8);  bg[(j0)+1][1] = LDSB(slot, bbB, 32 + h8); }

// 8 MFMA: rows i0,i0+1 x cols j0,j0+1
#define MFMA_H(i0, AF, j0)                                                                \
    __builtin_amdgcn_s_setprio(1);                                                        \
    _Pragma("unroll")                                                                     \
    for (int jj = 0; jj < 2; ++jj) {                                                      \
        const int j = (j0) + jj;                                                          \
        acc[i0][j]     = __builtin_amdgcn_mfma_f32_16x16x32_bf16(AF[0], bg[j][0], acc[i0][j], 0, 0, 0);     \
        acc[i0][j]     = __builtin_amdgcn_mfma_f32_16x16x32_bf16(AF[1], bg[j][1], acc[i0][j], 0, 0, 0);     \
        acc[(i0)+1][j] = __builtin_amdgcn_mfma_f32_16x16x32_bf16(AF[2], bg[j][0], acc[(i0)+1][j], 0, 0, 0); \
        acc[(i0)+1][j] = __builtin_amdgcn_mfma_f32_16x16x32_bf16(AF[3], bg[j][1], acc[(i0)+1][j], 0, 0, 0); \
    }                                                                                     \
    __builtin_amdgcn_s_setprio(0);

// One K-tile.  tb=t&1; BRD: B read slot (t%3); BWR: B stage slot ((t+2)%3).
// STA: stage A(t+1); STB: stage B(t+2); VMC: 4 / 0 / -1 (skip).
#define TILE_BODY(tb, t, STA, STB, VMC, BRD, BWR)                                         \
  {                                                                                       \
    /* -- s00: af0->P, bg01 | bg23, af1->Q; stage A(0,0); drain af0+bg01 -- */            \
    RD_AF(afP, tb, 0)                                                                     \
    RD_BGH(BRD, 0)                                                                        \
    __builtin_amdgcn_sched_barrier(0);   /* {af0,bg01} oldest (drain boundary) */         \
    RD_BGH(BRD, 2)                                                                        \
    RD_AF(afQ, tb, 1)                                                                     \
    if (STA) STAGE_A(tb ^ 1, 0, 0, (t) + 1)                                               \
    WAITLG(8)                                                                             \
    MFMA_H(0, afP, 0)                                                                     \
    /* -- s01: af2->R; stage A(0,1); drain bg23 -- */                                     \
    RD_AF(afR, tb, 2)                                                                     \
    if (STA) STAGE_A(tb ^ 1, 0, 1, (t) + 1)                                               \
    WAITLG(8)                                                                             \
    MFMA_H(0, afP, 2)                                                                     \
    /* -- s10: af3->P (af0 dead); stage A(1,0); drain af1 -- */                           \
    RD_AF(afP, tb, 3)                                                                     \
    if (STA) STAGE_A(tb ^ 1, 1, 0, (t) + 1)                                               \
    WAITLG(8)                                                                             \
    MFMA_H(2, afQ, 0)                                                                     \
    /* -- s11: stage A(1,1); no wait (af1,bg23 already drained) -- */                     \
    if (STA) STAGE_A(tb ^ 1, 1, 1, (t) + 1)                                               \
    MFMA_H(2, afQ, 2)                                                                     \
    /* -- s20: stage B(0,0); drain af2 -- */                                              \
    if (STB) STAGE_B(BWR, 0, 0, (t) + 2)                                                  \
    WAITLG(4)                                                                             \
    MFMA_H(4, afR, 0)                                                                     \
    /* -- s21: stage B(0,1); no wait -- */                                                \
    if (STB) STAGE_B(BWR, 0, 1, (t) + 2)                                                  \
    MFMA_H(4, afR, 2)                                                                     \
    /* -- s30: stage B(1,0); drain af3 (2 subphases old) -- */                            \
    if (STB) STAGE_B(BWR, 1, 0, (t) + 2)                                                  \
    WAITLG(0)                                                                             \
    MFMA_H(6, afP, 0)                                                                     \
    /* -- s31: stage B(1,1); counted vmcnt; sole barrier -- */                            \
    if (STB) STAGE_B(BWR, 1, 1, (t) + 2)                                                  \
    MFMA_H(6, afP, 2)                                                                     \
    if ((VMC) == 4)      { asm volatile("s_waitcnt vmcnt(4)" ::: "memory"); }             \
    else if ((VMC) == 0) { asm volatile("s_waitcnt vmcnt(0)" ::: "memory"); }             \
    __builtin_amdgcn_s_barrier();  /* staged A(t+1)/B(t+1) collectively visible */        \
  }

__global__ __launch_bounds__(512, 2) void gemm_pipe7_kernel(
    const ushort* __restrict__ A,    // [M][K] bf16 bits
    const ushort* __restrict__ Bt,   // [N][K] bf16 bits
    const float* __restrict__ bias,  // [N]
    float* __restrict__ C) {         // [M][N]

    __shared__ ushort As[2][256][64];   // 64 KB
    __shared__ ushort Bs[3][256][64];   // 96 KB (3-slot B rotation)

    const int tid  = threadIdx.x;
    const int lane = tid & 63;
    const int wv   = tid >> 6;          // wave 0..7
    const int wmr  = wv >> 2;           // 0..1  (M)
    const int wcn  = wv & 3;            // 0..3  (N)
    const int r    = lane & 15;
    const int h8   = (lane >> 4) << 3;  // 0,8,16,24 (ushort col of k-frag)

    // bijective XCD swizzle (nwg = 512)
    const int nbn  = N_TOT / 256;                 // 8
    const int nwg  = (M_TOT / 256) * nbn;         // 512
    const int cpx  = nwg >> 3;
    const int swz  = (blockIdx.x & 7) * cpx + (blockIdx.x >> 3);
    const int brow = (swz / nbn) * 256;
    const int bcol = (swz % nbn) * 256;

    // staging: thread -> row tid>>3 of each 64-row group, 16B at pre-swizzled col
    const int srow = tid >> 3;
    const int scol = (((tid & 7) ^ (srow & 7)) << 3);
    const ushort* Agbase = A  + (size_t)(brow + srow) * K_TOT + scol;
    const ushort* Bgbase = Bt + (size_t)(bcol + srow) * K_TOT + scol;

    const int ab = wmr * 128 + r;       // wave's A row base

    f32x4 acc[8][4];
    const f32x4 zero = {0.f, 0.f, 0.f, 0.f};
    #pragma unroll
    for (int i = 0; i < 8; ++i)
        #pragma unroll
        for (int j = 0; j < 4; ++j) acc[i][j] = zero;

    // ---- prologue: A(0)->As0, B(0)->slot0, B(1)->slot1; vmcnt(4) drains
    //      A(0)+B(0) (oldest 8), keeps B(1) in flight; barrier ----
    STAGE_A(0, 0, 0, 0) STAGE_A(0, 0, 1, 0) STAGE_A(0, 1, 0, 0) STAGE_A(0, 1, 1, 0)
    STAGE_B(0, 0, 0, 0) STAGE_B(0, 0, 1, 0) STAGE_B(0, 1, 0, 0) STAGE_B(0, 1, 1, 0)
    STAGE_B(1, 0, 0, 1) STAGE_B(1, 0, 1, 1) STAGE_B(1, 1, 0, 1) STAGE_B(1, 1, 1, 1)
    asm volatile("s_waitcnt vmcnt(4)" ::: "memory");
    __builtin_amdgcn_s_barrier();

    bf16x8 afP[4], afQ[4], afR[4];
    bf16x8 bg[4][2];

    int brd = 0;   // B read slot  = t%3
    int bwr = 2;   // B stage slot = (t+2)%3

    for (int t = 0; t < NT - 4; t += 2) {
        TILE_BODY(0, t,     1, 1, 4, brd, bwr)
        brd = (brd == 2) ? 0 : brd + 1;  bwr = (bwr == 2) ? 0 : bwr + 1;
        TILE_BODY(1, t + 1, 1, 1, 4, brd, bwr)
        brd = (brd == 2) ? 0 : brd + 1;  bwr = (bwr == 2) ? 0 : bwr + 1;
    }
    TILE_BODY(0, NT - 4, 1, 1, 4, brd, bwr)   // t=28: stage A(29), B(30)
    brd = (brd == 2) ? 0 : brd + 1;  bwr = (bwr == 2) ? 0 : bwr + 1;
    TILE_BODY(1, NT - 3, 1, 1, 4, brd, bwr)   // t=29: stage A(30), B(31); keeps B(31)
    brd = (brd == 2) ? 0 : brd + 1;
    TILE_BODY(0, NT - 2, 1, 0, 0, brd, 0)     // t=30: stage A(31); drain all
    brd = (brd == 2) ? 0 : brd + 1;
    TILE_BODY(1, NT - 1, 0, 0, -1, brd, 0)    // t=31: pure compute

    // ---- epilogue: bias + store (C/D layout: col=lane&15, row=(lane>>4)*4+reg)
    const int hq = (lane >> 4) * 4;
    float bv[4];
    #pragma unroll
    for (int j = 0; j < 4; ++j) bv[j] = bias[bcol + wcn * 64 + j * 16 + r];
    #pragma unroll
    for (int i = 0; i < 8; ++i) {
        const int row0 = brow + wmr * 128 + i * 16 + hq;
        #pragma unroll
        for (int j = 0; j < 4; ++j) {
            const int col = bcol + wcn * 64 + j * 16 + r;
            #pragma unroll
            for (int jj = 0; jj < 4; ++jj)
                C[(size_t)(row0 + jj) * N_TOT + col] = acc[i][j][jj] + bv[j];
        }
    }
}

extern "C" void kernel_launch(void* const* d_in, const int* in_sizes, int n_in,
                              void* d_out, int out_size, void* d_ws, size_t ws_size,
                              hipStream_t stream) {
    const float* x    = (const float*)d_in[0];   // [4,4096,2048]
    const float* wgt  = (const float*)d_in[1];   // [2048,2048]
    const float* bias = (const float*)d_in[2];   // [2048]
    float* out = (float*)d_out;                  // [4,4096,2048]

    ushort* qx = (ushort*)d_ws;                          // 64 MB
    ushort* qw = qx + (size_t)M_TOT * K_TOT;             // 8 MB

    quant_fused_kernel<<<QW_BLOCKS + (M_TOT * K_TOT / 4) / 256, 256, 0, stream>>>(x, wgt, qx, qw);
    gemm_pipe7_kernel<<<(M_TOT / 256) * (N_TOT / 256), 512, 0, stream>>>(qx, qw, bias, out);
}

// Round 14
// 161.826 us; speedup vs baseline: 1.0117x; 1.0117x over previous
//
#include <hip/hip_runtime.h>
#include <hip/hip_bf16.h>
#include <stdint.h>

#define M_TOT 16384
#define N_TOT 2048
#define K_TOT 2048
#define NT 32            // K-tiles of BK=64
#define QW_BLOCKS 1024   // quant_w blocks (4096 tiles / 4 waves per block)

typedef __attribute__((ext_vector_type(8))) short bf16x8;
typedef __attribute__((ext_vector_type(4))) float f32x4;

__device__ __forceinline__ ushort f32_to_bf16_rne(float f) {
    uint32_t u = __float_as_uint(f);
    uint32_t r = (u + 0x7fffu + ((u >> 16) & 1u)) >> 16;
    return (ushort)r;
}

__device__ __forceinline__ void async_copy16(const void* gptr, void* lptr) {
    __builtin_amdgcn_global_load_lds(
        (const __attribute__((address_space(1))) uint32_t*)gptr,
        (__attribute__((address_space(3))) uint32_t*)lptr,
        16, 0, 0);
}

// ---------------------------------------------------------------------------
// Merged fake-quant kernel.  Blocks [0, QW_BLOCKS): weight 32x32 tiles
// (scheduled first, finish early).  Blocks [QW_BLOCKS, ...): x rows,
// per (row, 32-col) block, 8 lanes per block via shfl_xor maxabs.
// At BW floor: 201 MB @ ~5.4 TB/s ~= 37 us.
// ---------------------------------------------------------------------------
__global__ void quant_fused_kernel(const float* __restrict__ x,
                                   const float* __restrict__ w,
                                   ushort* __restrict__ qx,
                                   ushort* __restrict__ qw) {
    if (blockIdx.x < QW_BLOCKS) {
        const int gtid = blockIdx.x * 256 + threadIdx.x;
        const int wid  = gtid >> 6;
        const int lane = gtid & 63;
        const int tn = wid >> 6;
        const int tk = wid & 63;
        const int row = tn * 32 + (lane >> 1);
        const int col = tk * 32 + ((lane & 1) << 4);
        const float* p = w + (size_t)row * K_TOT + col;
        const float4 v0 = ((const float4*)p)[0];
        const float4 v1 = ((const float4*)p)[1];
        const float4 v2 = ((const float4*)p)[2];
        const float4 v3 = ((const float4*)p)[3];
        float m = 0.f;
#define MAX4(V) m = fmaxf(m, fmaxf(fmaxf(fabsf(V.x), fabsf(V.y)), fmaxf(fabsf(V.z), fabsf(V.w))));
        MAX4(v0) MAX4(v1) MAX4(v2) MAX4(v3)
#undef MAX4
        #pragma unroll
        for (int off = 1; off < 64; off <<= 1) m = fmaxf(m, __shfl_xor(m, off));
        const float s = (m > 0.f) ? (m / 127.f) : 1.f;
        float vv[16] = {v0.x, v0.y, v0.z, v0.w, v1.x, v1.y, v1.z, v1.w,
                        v2.x, v2.y, v2.z, v2.w, v3.x, v3.y, v3.z, v3.w};
        union { ushort us[16]; uint4 q[2]; } o;
        #pragma unroll
        for (int i = 0; i < 16; ++i) {
            const float q = fminf(fmaxf(rintf(vv[i] / s), -127.f), 127.f) * s;
            o.us[i] = f32_to_bf16_rne(q);
        }
        uint4* dst = (uint4*)(qw + (size_t)row * K_TOT + col);
        dst[0] = o.q[0];
        dst[1] = o.q[1];
    } else {
        const int tid = (blockIdx.x - QW_BLOCKS) * 256 + threadIdx.x;
        const float4 v = ((const float4*)x)[tid];
        float m = fmaxf(fmaxf(fabsf(v.x), fabsf(v.y)), fmaxf(fabsf(v.z), fabsf(v.w)));
        m = fmaxf(m, __shfl_xor(m, 1));
        m = fmaxf(m, __shfl_xor(m, 2));
        m = fmaxf(m, __shfl_xor(m, 4));
        const float s = (m > 0.f) ? (m / 127.f) : 1.f;
        const float q0 = fminf(fmaxf(rintf(v.x / s), -127.f), 127.f) * s;
        const float q1 = fminf(fmaxf(rintf(v.y / s), -127.f), 127.f) * s;
        const float q2 = fminf(fmaxf(rintf(v.z / s), -127.f), 127.f) * s;
        const float q3 = fminf(fmaxf(rintf(v.w / s), -127.f), 127.f) * s;
        ushort4 r;
        r.x = f32_to_bf16_rne(q0);
        r.y = f32_to_bf16_rne(q1);
        r.z = f32_to_bf16_rne(q2);
        r.w = f32_to_bf16_rne(q3);
        ((ushort4*)qx)[tid] = r;
    }
}

// ---------------------------------------------------------------------------
// 256x256 bf16 GEMM — best measured (R9/R12): flattened-read schedule,
// B triple-buffered (no mid-tile barrier), ONE barrier/tile, counted
// vmcnt(4) keeps B(t+2) in flight.  LDS: As[2] 64KB + Bs[3] 96KB = 160KB.
// lgkm trace (per wave): p0 wait drains bg8+afX4 (leaves afY); p1 drains afY
// (leaves afX); p2 drains afX (leaves afY); p3 lgkm(0).
// Measured: ~125 us, MfmaUtil ~47%, bank conflicts 0.
// ---------------------------------------------------------------------------
#define LDSA(tb, row, colus) \
    (*(const bf16x8*)&As[tb][row][(colus) ^ (((row) & 7) << 3)])
#define LDSB(slot, row, colus) \
    (*(const bf16x8*)&Bs[slot][row][(colus) ^ (((row) & 7) << 3)])

#define STAGE_A(tb, hh, li, tt)                                                          \
    async_copy16(Agbase + (size_t)((hh) * 128 + (li) * 64) * K_TOT + (size_t)(tt) * 64,  \
                 (char*)&As[0][0][0] + (tb) * 32768 + (hh) * 16384 + (li) * 8192 + (wv << 10));
#define STAGE_B(slot, hh, li, tt)                                                        \
    async_copy16(Bgbase + (size_t)((hh) * 128 + (li) * 64) * K_TOT + (size_t)(tt) * 64,  \
                 (char*)&Bs[0][0][0] + (size_t)(slot) * 32768 + (hh) * 16384 + (li) * 8192 + (wv << 10));
#define STAGE_A2(tb, hh, tt)    { STAGE_A(tb, hh, 0, tt) STAGE_A(tb, hh, 1, tt) }
#define STAGE_B2(slot, hh, tt)  { STAGE_B(slot, hh, 0, tt) STAGE_B(slot, hh, 1, tt) }

#define WAITLGKM4 { asm volatile("s_waitcnt lgkmcnt(4)" ::: "memory"); __builtin_amdgcn_sched_barrier(0); }
#define WAITLGKM0 { asm volatile("s_waitcnt lgkmcnt(0)" ::: "memory"); __builtin_amdgcn_sched_barrier(0); }

// read the 4 A-fragments of row-pair q (rows q*32, q*32+16; k lo/hi halves)
#define RD_AF(DST, tb, q) {                                   \
    DST[0] = LDSA(tb, ab + (q) * 32,      h8);                \
    DST[1] = LDSA(tb, ab + (q) * 32,      32 + h8);           \
    DST[2] = LDSA(tb, ab + (q) * 32 + 16, h8);                \
    DST[3] = LDSA(tb, ab + (q) * 32 + 16, 32 + h8); }

#define RD_BG(slot) {                                                         \
    _Pragma("unroll")                                                         \
    for (int j = 0; j < 4; ++j) {                                             \
        const int bb = wcn * 64 + j * 16 + r;                                 \
        bg[j][0] = LDSB(slot, bb, h8);  bg[j][1] = LDSB(slot, bb, 32 + h8);   \
    } }

#define MFMA_PH(i0, AF)                                                                   \
    __builtin_amdgcn_s_setprio(1);                                                        \
    _Pragma("unroll")                                                                     \
    for (int j = 0; j < 4; ++j) {                                                         \
        acc[i0][j]     = __builtin_amdgcn_mfma_f32_16x16x32_bf16(AF[0], bg[j][0], acc[i0][j], 0, 0, 0);     \
        acc[i0][j]     = __builtin_amdgcn_mfma_f32_16x16x32_bf16(AF[1], bg[j][1], acc[i0][j], 0, 0, 0);     \
        acc[(i0)+1][j] = __builtin_amdgcn_mfma_f32_16x16x32_bf16(AF[2], bg[j][0], acc[(i0)+1][j], 0, 0, 0); \
        acc[(i0)+1][j] = __builtin_amdgcn_mfma_f32_16x16x32_bf16(AF[3], bg[j][1], acc[(i0)+1][j], 0, 0, 0); \
    }                                                                                     \
    __builtin_amdgcn_s_setprio(0);

// One K-tile.  tb = t&1 (A buffer).  BRD: B read slot (t%3); BWR: B stage
// slot ((t+2)%3).  STA/STB gate staging; VMC: 4 / 0 / -1 (skip).
#define TILE_BODY(tb, t, STA, STB, VMC, BRD, BWR)                                         \
  {                                                                                       \
    /* -- p0: afX(q0) + bg(8) + afY(q1); stage A(t+1)h0; drain afX+bg -- */               \
    RD_AF(afX, tb, 0)                                                                     \
    RD_BG(BRD)                                                                            \
    RD_AF(afY, tb, 1)                                                                     \
    if (STA) STAGE_A2(tb ^ 1, 0, (t) + 1)                                                 \
    WAITLGKM4                                                                             \
    MFMA_PH(0, afX)                                                                       \
    /* -- p1: afX(q2); stage A(t+1)h1; drain afY -- */                                    \
    RD_AF(afX, tb, 2)                                                                     \
    if (STA) STAGE_A2(tb ^ 1, 1, (t) + 1)                                                 \
    WAITLGKM4                                                                             \
    MFMA_PH(2, afY)                                                                       \
    /* -- p2: afY(q3); stage B(t+2)h0 into disjoint slot; drain afX -- */                 \
    RD_AF(afY, tb, 3)                                                                     \
    if (STB) STAGE_B2(BWR, 0, (t) + 2)                                                    \
    WAITLGKM4                                                                             \
    MFMA_PH(4, afX)                                                                       \
    /* -- p3: stage B(t+2)h1; drain afY; counted vmcnt; sole barrier -- */                \
    if (STB) STAGE_B2(BWR, 1, (t) + 2)                                                    \
    WAITLGKM0                                                                             \
    MFMA_PH(6, afY)                                                                       \
    if ((VMC) == 4)      { asm volatile("s_waitcnt vmcnt(4)" ::: "memory"); }             \
    else if ((VMC) == 0) { asm volatile("s_waitcnt vmcnt(0)" ::: "memory"); }             \
    __builtin_amdgcn_s_barrier();  /* staged A(t+1)/B(t+1) collectively visible */        \
  }

__global__ __launch_bounds__(512, 2) void gemm_pipe5_kernel(
    const ushort* __restrict__ A,    // [M][K] bf16 bits
    const ushort* __restrict__ Bt,   // [N][K] bf16 bits
    const float* __restrict__ bias,  // [N]
    float* __restrict__ C) {         // [M][N]

    __shared__ ushort As[2][256][64];   // 64 KB
    __shared__ ushort Bs[3][256][64];   // 96 KB (triple-buffered B)

    const int tid  = threadIdx.x;
    const int lane = tid & 63;
    const int wv   = tid >> 6;          // wave 0..7
    const int wmr  = wv >> 2;           // 0..1  (M)
    const int wcn  = wv & 3;            // 0..3  (N)
    const int r    = lane & 15;
    const int h8   = (lane >> 4) << 3;  // 0,8,16,24 (ushort col of k-frag)

    // bijective XCD swizzle (nwg = 512)
    const int nbn  = N_TOT / 256;                 // 8
    const int nwg  = (M_TOT / 256) * nbn;         // 512
    const int cpx  = nwg >> 3;
    const int swz  = (blockIdx.x & 7) * cpx + (blockIdx.x >> 3);
    const int brow = (swz / nbn) * 256;
    const int bcol = (swz % nbn) * 256;

    // staging: thread -> row tid>>3 of each 64-row group, 16B at pre-swizzled col
    const int srow = tid >> 3;
    const int scol = (((tid & 7) ^ (srow & 7)) << 3);
    const ushort* Agbase = A  + (size_t)(brow + srow) * K_TOT + scol;
    const ushort* Bgbase = Bt + (size_t)(bcol + srow) * K_TOT + scol;

    const int ab = wmr * 128 + r;       // wave's A row base

    f32x4 acc[8][4];
    const f32x4 zero = {0.f, 0.f, 0.f, 0.f};
    #pragma unroll
    for (int i = 0; i < 8; ++i)
        #pragma unroll
        for (int j = 0; j < 4; ++j) acc[i][j] = zero;

    // ---- prologue: A(0)->As0, B(0)->slot0, B(1)->slot1; vmcnt(4) keeps B(1)
    //      in flight; barrier ----
    STAGE_A2(0, 0, 0) STAGE_A2(0, 1, 0)
    STAGE_B2(0, 0, 0) STAGE_B2(0, 1, 0)
    STAGE_B2(1, 0, 1) STAGE_B2(1, 1, 1)
    asm volatile("s_waitcnt vmcnt(4)" ::: "memory");
    __builtin_amdgcn_s_barrier();

    bf16x8 afX[4], afY[4];
    bf16x8 bg[4][2];

    int brd = 0;   // B read slot  = t%3
    int bwr = 2;   // B stage slot = (t+2)%3

    for (int t = 0; t < NT - 2; t += 2) {
        TILE_BODY(0, t,     1, 1, 4, brd, bwr)
        brd = (brd == 2) ? 0 : brd + 1;  bwr = (bwr == 2) ? 0 : bwr + 1;
        TILE_BODY(1, t + 1, 1, 1, 4, brd, bwr)
        brd = (brd == 2) ? 0 : brd + 1;  bwr = (bwr == 2) ? 0 : bwr + 1;
    }
    TILE_BODY(0, NT - 2, 1, 0, 0, brd, 0)    // stage A(31) only; drain all
    brd = (brd == 2) ? 0 : brd + 1;
    TILE_BODY(1, NT - 1, 0, 0, -1, brd, 0)   // pure compute

    // ---- epilogue: bias + store (C/D layout: col=lane&15, row=(lane>>4)*4+reg)
    const int hq = (lane >> 4) * 4;
    float bv[4];
    #pragma unroll
    for (int j = 0; j < 4; ++j) bv[j] = bias[bcol + wcn * 64 + j * 16 + r];
    #pragma unroll
    for (int i = 0; i < 8; ++i) {
        const int row0 = brow + wmr * 128 + i * 16 + hq;
        #pragma unroll
        for (int j = 0; j < 4; ++j) {
            const int col = bcol + wcn * 64 + j * 16 + r;
            #pragma unroll
            for (int jj = 0; jj < 4; ++jj)
                C[(size_t)(row0 + jj) * N_TOT + col] = acc[i][j][jj] + bv[j];
        }
    }
}

extern "C" void kernel_launch(void* const* d_in, const int* in_sizes, int n_in,
                              void* d_out, int out_size, void* d_ws, size_t ws_size,
                              hipStream_t stream) {
    const float* x    = (const float*)d_in[0];   // [4,4096,2048]
    const float* wgt  = (const float*)d_in[1];   // [2048,2048]
    const float* bias = (const float*)d_in[2];   // [2048]
    float* out = (float*)d_out;                  // [4,4096,2048]

    ushort* qx = (ushort*)d_ws;                          // 64 MB
    ushort* qw = qx + (size_t)M_TOT * K_TOT;             // 8 MB

    quant_fused_kernel<<<QW_BLOCKS + (M_TOT * K_TOT / 4) / 256, 256, 0, stream>>>(x, wgt, qx, qw);
    gemm_pipe5_kernel<<<(M_TOT / 256) * (N_TOT / 256), 512, 0, stream>>>(qx, qw, bias, out);
}